// Round 1
// baseline (780.155 us; speedup 1.0000x reference)
//
#include <hip/hip_runtime.h>
#include <hip/hip_bf16.h>

// TransducerJoint: h[b,t,u,:] = f[b,t,:] + g[b,u,:] when t<f_len[b] && u<g_len[b], else 0.
// B=16, T=256, U=96, H=512, fp32. Write-bound: 805 MB out vs ~11 MB in.
// One block per (b,t,u) row; 128 threads x float4 = 512 floats (2KB contiguous store).

#define TJ_B 16
#define TJ_T 256
#define TJ_U 96
#define TJ_H 512
#define TJ_H4 (TJ_H / 4)   // 128 float4 per row

__global__ __launch_bounds__(TJ_H4) void TransducerJoint_66915590472509_kernel(
    const float4* __restrict__ f,   // (B, T, H/4)
    const float4* __restrict__ g,   // (B, U, H/4)
    const int* __restrict__ f_len,  // (B,)
    const int* __restrict__ g_len,  // (B,)
    float4* __restrict__ out)       // (B, T, U, H/4)
{
    const int bid = blockIdx.x;            // b*T*U + t*U + u
    const int u  = bid % TJ_U;
    const int bt = bid / TJ_U;             // b*T + t
    const int t  = bt % TJ_T;
    const int b  = bt / TJ_T;
    const int h4 = threadIdx.x;            // 0..127

    // Block-uniform mask (scalar branch, no divergence).
    const bool valid = (t < f_len[b]) && (u < g_len[b]);

    float4 res;
    if (valid) {
        const float4 fv = f[(size_t)(b * TJ_T + t) * TJ_H4 + h4];
        const float4 gv = g[(size_t)(b * TJ_U + u) * TJ_H4 + h4];
        res = make_float4(fv.x + gv.x, fv.y + gv.y, fv.z + gv.z, fv.w + gv.w);
    } else {
        res = make_float4(0.f, 0.f, 0.f, 0.f);  // harness poisons d_out; must zero.
    }
    out[(size_t)bid * TJ_H4 + h4] = res;
}

extern "C" void kernel_launch(void* const* d_in, const int* in_sizes, int n_in,
                              void* d_out, int out_size, void* d_ws, size_t ws_size,
                              hipStream_t stream) {
    const float4* f     = (const float4*)d_in[0];
    const float4* g     = (const float4*)d_in[1];
    const int*    f_len = (const int*)d_in[2];
    const int*    g_len = (const int*)d_in[3];
    float4*       out   = (float4*)d_out;

    const int nblocks = TJ_B * TJ_T * TJ_U;  // 393,216
    TransducerJoint_66915590472509_kernel<<<nblocks, TJ_H4, 0, stream>>>(
        f, g, f_len, g_len, out);
}